// Round 10
// baseline (131.205 us; speedup 1.0000x reference)
//
#include <hip/hip_runtime.h>
#include <cfloat>
#include <stdint.h>

// KmeansVectorQuantizer: B=8, T=2048, G=8, D=64, V=1024
// Outputs (flat f32): ids[B*T*G], quantized_st[B*T*G*D], kmeans, commit, total
#define G_ 8
#define D_ 64
#define V_ 1024
#define BT_ 16384
#define TPB_ 256              // vq_scan: 4 waves
#define NSLOT_ 128            // spread loss-accumulator slots
#define TOKS_ 128             // tokens per scan block
#define NC_ 64                // codewords per chunk
#define NCHUNK_ (V_ / NC_)    // 16 chunks

typedef unsigned long long u64;
typedef uint32_t u32;
typedef _Float16 h8 __attribute__((ext_vector_type(8)));
typedef float f32x4 __attribute__((ext_vector_type(4)));

typedef __attribute__((address_space(3))) uint32_t lds_u32;
typedef __attribute__((address_space(1))) uint32_t glb_u32;

// global->LDS DMA, 16B per lane; LDS dest = wave-uniform base + lane*16
#define GL2LDS(gsrc, ldst) \
    __builtin_amdgcn_global_load_lds((glb_u32*)(gsrc), (lds_u32*)(ldst), 16, 0, 0)

// ws layout (bytes):
//   [0..511]     float part[128]        loss partial slots (memset 0)
//   [512..515]   int   cnt_active       (memset 0)
//   [1024)       float csqT[G_*V_]      32 KB  (transposed [g][v])
//   [33792)      int   list[BT_]        64 KB
//   [131072)     f16   cbH[G_*V_*64]    1 MB   codebook hi, GROUP-MAJOR [g][v][d]
//   [1179648)    f16   cbL[G_*V_*64]    1 MB   codebook lo*2^12, [g][v][d]

// Full-device prep (R8/R9): 256 blocks x 256 thr.
// Phase A: one thread per 8 codebook elems -- coalesced f32x8 load, f16 hi/lo
//          convert (stored group-major), csq row-sum via 3-step shfl_xor.
// Phase B: each block compacts its 64 tokens (wave 0: ballot + 1 atomicAdd).
// Phase C: coalesced zero-fill of padded tokens.
__global__ __launch_bounds__(256) void prep_csq(
        const float* __restrict__ cb, const int* __restrict__ pad,
        float* __restrict__ csqT,
        int* __restrict__ cnt, int* __restrict__ list,
        float* __restrict__ out_ids, float* __restrict__ out_q,
        _Float16* __restrict__ cbH, _Float16* __restrict__ cbL) {
    const int tid = threadIdx.x;
    const int bx  = blockIdx.x;              // 0..255
    const int lane = tid & 63, w = tid >> 6;

    // ---- Phase A: codebook convert + csq (group-major store) ----
    {
        const int gid = bx * 256 + tid;      // 0..65535
        const int row = gid >> 3;            // (v,g) row, 0..8191  (= v*8+g)
        const int seg = gid & 7;             // 8-elem segment within row
        const int v   = row >> 3, gg = row & 7;
        const float4* r = (const float4*)(cb + (size_t)row * 64 + seg * 8);
        float4 c0 = r[0], c1 = r[1];
        float xs[8] = {c0.x, c0.y, c0.z, c0.w, c1.x, c1.y, c1.z, c1.w};
        h8 hv, lv;
        float s = 0.f;
#pragma unroll
        for (int e = 0; e < 8; ++e) {
            s += xs[e] * xs[e];
            _Float16 hh = (_Float16)xs[e];
            hv[e] = hh;
            lv[e] = (_Float16)((xs[e] - (float)hh) * 4096.f);
        }
        const size_t dst = ((size_t)gg * V_ + v) * 64 + seg * 8;
        *(h8*)(cbH + dst) = hv;
        *(h8*)(cbL + dst) = lv;
        s += __shfl_xor(s, 1, 64);           // row's 8 lanes are consecutive
        s += __shfl_xor(s, 2, 64);
        s += __shfl_xor(s, 4, 64);
        if (seg == 0) csqT[gg * V_ + v] = s;
    }

    // ---- Phase B: compaction of this block's 64 tokens (wave 0) ----
    __shared__ int s_plist[64];
    __shared__ int s_npl;
    if (w == 0) {
        int tok = bx * 64 + lane;
        bool active = (pad[tok] == 0);
        u64 bal = __ballot(active);
        int na  = __popcll(bal);
        int base = 0;
        if (lane == 0) base = atomicAdd(cnt, na);
        base = __shfl(base, 0, 64);
        const u64 mb = ((u64)1 << lane) - 1;
        if (active) list[base + __popcll(bal & mb)] = tok;
        else        s_plist[__popcll(~bal & mb)] = tok;
        if (lane == 0) s_npl = 64 - na;
    }
    __syncthreads();

    // ---- Phase C: zero-fill padded tokens (2 KB per wave-iter, coalesced) --
    const int npl = s_npl;
    for (int i = w; i < npl; i += 4) {
        int tok = s_plist[i];
        float4 z = make_float4(0.f, 0.f, 0.f, 0.f);
        float4* q = (float4*)(out_q + (size_t)tok * (G_ * D_)) + lane * 2;
        q[0] = z;
        q[1] = z;
        if (lane < G_) out_ids[(size_t)tok * G_ + lane] = -1.0f;
    }
}

// MFMA scan, R10: WAVE-PRIVATE staging -- ZERO in-loop barriers.
// block = 128 tok x 1024 cw (one g), 4 waves (mh x nh). Each wave stages its
// own 32-row half-chunk (4 KB H + 4 KB L) into a private LDS region and is
// its only reader -> no cross-wave dependency -> no s_barrier in the loop.
// Waves free-run: {lgkmcnt(0); issue chunk c+1 (8 DMA); vmcnt(8) [c landed,
// c+1 in flight]; compute c}. The lgkmcnt(0) at iteration top proves this
// wave's reads of c-1 are done before c+1's DMA can overwrite that buffer.
// Convoy-free waves at staggered phases interleave MFMA/VALU across pipes
// (R6-R9 showed ~50% idle from phase-lockstep). 2x DMA duplication (nh pairs
// stage the same rows) is far under the L2 ceiling. Per-lane fragment bytes,
// MFMA chain, fold identical to R9 -> ids bit-exact.
__global__ __launch_bounds__(TPB_, 2) void vq_scan(
    const float* __restrict__ inp,
    const float* __restrict__ cb,
    const float* __restrict__ csqT,
    const int* __restrict__ cnt,
    const int* __restrict__ list,
    const _Float16* __restrict__ cbH,
    const _Float16* __restrict__ cbL,
    float* __restrict__ out_ids,
    float* __restrict__ out_q,
    float* __restrict__ part) {

    __shared__ __align__(16) unsigned char BH[2][4][4096];  // 32 KB f16 hi (per-wave)
    __shared__ __align__(16) unsigned char BL[2][4][4096];  // 32 KB f16 lo (per-wave)
    __shared__ float csq_s[V_];                             //  4 KB
    __shared__ u64 merge_s[2][TOKS_];                       //  2 KB

    const int nact = cnt[0];
    const int tile = blockIdx.x;
    if (tile * TOKS_ >= nact) return;          // uniform early-exit (pre-barrier)
    const int g    = blockIdx.y;
    const int tid  = threadIdx.x;
    const int lane = tid & 63;
    const int w    = tid >> 6;          // 0..3
    const int mh   = w >> 1;            // token half  (0..1)
    const int nh   = w & 1;             // column half (0..1)
    const int r16  = lane & 15;
    const int kq   = lane >> 4;

    // ---- A fragments FIRST (their waitcnts then don't drain the DMA queue) --
    h8 AH[4][2], AL[4][2];
#pragma unroll
    for (int rf = 0; rf < 4; ++rf) {
        int p = tile * TOKS_ + mh * 64 + rf * 16 + r16;
        int tok = list[p < nact ? p : 0];
        const float* xr = inp + (size_t)tok * (G_ * D_) + g * D_;
#pragma unroll
        for (int kf = 0; kf < 2; ++kf) {
            const float4* xp = (const float4*)(xr + kf * 32 + kq * 8);
            float4 a = xp[0], b = xp[1];
            float xs[8] = {a.x, a.y, a.z, a.w, b.x, b.y, b.z, b.w};
#pragma unroll
            for (int e = 0; e < 8; ++e) {
                _Float16 hh = (_Float16)xs[e];
                AH[rf][kf][e] = hh;
                AL[rf][kf][e] = (_Float16)((xs[e] - (float)hh) * 4096.f);
            }
        }
    }

    // per-lane DMA source (group-major, wave-private): wave (nh) needs local
    // rows lr = 0..31 (global col = nh*32 + lr) of each 64-row chunk. Per 1KB
    // op i: lr = i*8 + (lane>>3), blk = lane&7; inverse-swizzle source block
    // so LDS[lr][blk] = logical[lr][blk ^ (lr&7)]  (lr&7 == lane>>3 here).
    const size_t soff = (size_t)(lane >> 3) * 128
                      + (size_t)(((lane & 7) ^ (lane >> 3)) * 16);
    const unsigned char* sH = (const unsigned char*)cbH
                            + (size_t)g * 131072 + (size_t)nh * 4096 + soff;
    const unsigned char* sL = (const unsigned char*)cbL
                            + (size_t)g * 131072 + (size_t)nh * 4096 + soff;

    // ---- prologue: issue chunk 0 into buf 0 (8 DMA ops/wave) ----
#pragma unroll
    for (int i = 0; i < 4; ++i) GL2LDS(sH + i * 1024, &BH[0][0][0] + (size_t)w * 4096 + i * 1024);
#pragma unroll
    for (int i = 0; i < 4; ++i) GL2LDS(sL + i * 1024, &BL[0][0][0] + (size_t)w * 4096 + i * 1024);

    csq_s[tid]       = csqT[g * V_ + tid];
    csq_s[tid + 256] = csqT[g * V_ + tid + 256];
    csq_s[tid + 512] = csqT[g * V_ + tid + 512];
    csq_s[tid + 768] = csqT[g * V_ + tid + 768];

    float beste[16];
    int   bestid[16];
#pragma unroll
    for (int s = 0; s < 16; ++s) { beste[s] = -FLT_MAX / 2; bestid[s] = 0; }

    __syncthreads();   // csq_s visible to all waves (single barrier, pre-loop)

    // b-frag byte within wave region: lr = cf*16 + r16;
    // byte = lr*128 + kq*16, swizzled ^((r16&7)<<4) (r16&7 == lr&7)
    const u32 o0 = (u32)(((r16 * 128 + kq * 16)) ^ ((u32)(r16 & 7) << 4));

#pragma unroll 1
    for (int c = 0; c < NCHUNK_; ++c) {
        // this wave's reads of chunk c-1 (same buffer c+1 targets) are done:
        asm volatile("s_waitcnt lgkmcnt(0)" ::: "memory");

        if (c + 1 < NCHUNK_) {             // issue next chunk, private buffer
            const int b = (c + 1) & 1;
            const size_t adv = (size_t)(c + 1) * 8192;
            unsigned char* dH = &BH[b][0][0] + (size_t)w * 4096;
            unsigned char* dL = &BL[b][0][0] + (size_t)w * 4096;
#pragma unroll
            for (int i = 0; i < 4; ++i) GL2LDS(sH + adv + i * 1024, dH + i * 1024);
#pragma unroll
            for (int i = 0; i < 4; ++i) GL2LDS(sL + adv + i * 1024, dL + i * 1024);
            // chunk c landed; c+1's 8 ops stay in flight
            asm volatile("s_waitcnt vmcnt(8)" ::: "memory");
        } else {
            asm volatile("s_waitcnt vmcnt(0)" ::: "memory");
        }
        __builtin_amdgcn_sched_barrier(0);

        const unsigned char* BHc = &BH[c & 1][0][0] + (size_t)w * 4096;
        const unsigned char* BLc = &BL[c & 1][0][0] + (size_t)w * 4096;
#pragma unroll
        for (int cf = 0; cf < 2; ++cf) {
            const u32 ob = o0 + (u32)(cf * 2048);
            const h8 bh0 = *(const h8*)(BHc + ob);
            const h8 bh1 = *(const h8*)(BHc + (ob ^ 64));
            const h8 bl0 = *(const h8*)(BLc + ob);
            const h8 bl1 = *(const h8*)(BLc + (ob ^ 64));
            const int vcol = c * NC_ + nh * 32 + cf * 16 + r16;
            const float ai = -0.5f * csq_s[vcol];
#pragma unroll
            for (int rf = 0; rf < 4; ++rf) {
                f32x4 a  = {ai, ai, ai, ai};
                f32x4 ac = {0.f, 0.f, 0.f, 0.f};
                a  = __builtin_amdgcn_mfma_f32_16x16x32_f16(AH[rf][0], bh0, a,  0, 0, 0);
                a  = __builtin_amdgcn_mfma_f32_16x16x32_f16(AH[rf][1], bh1, a,  0, 0, 0);
                ac = __builtin_amdgcn_mfma_f32_16x16x32_f16(AH[rf][0], bl0, ac, 0, 0, 0);
                ac = __builtin_amdgcn_mfma_f32_16x16x32_f16(AH[rf][1], bl1, ac, 0, 0, 0);
                ac = __builtin_amdgcn_mfma_f32_16x16x32_f16(AL[rf][0], bh0, ac, 0, 0, 0);
                ac = __builtin_amdgcn_mfma_f32_16x16x32_f16(AL[rf][1], bh1, ac, 0, 0, 0);
#pragma unroll
                for (int q = 0; q < 4; ++q) {
                    // e = -d/2 exactly; argmax e == argmin d, ties -> first
                    float e = fmaf(0x1.0p-12f, ac[q], a[q]);
                    int s = rf * 4 + q;
                    if (e > beste[s]) { beste[s] = e; bestid[s] = vcol; }
                }
            }
        }
    }

    // ---- cross-lane argmin (16-lane butterfly) + cross-nh merge ----
#pragma unroll
    for (int s = 0; s < 16; ++s) {
        float d = -2.f * beste[s];
        u32 u = __float_as_uint(d);
        u = u ^ ((u >> 31) ? 0xFFFFFFFFu : 0x80000000u);   // sortable float
        u64 pk = ((u64)u << 32) | (u32)bestid[s];
#pragma unroll
        for (int off = 1; off <= 8; off <<= 1) {
            u64 o = __shfl_xor(pk, off, 64);
            pk = (o < pk) ? o : pk;
        }
        if (r16 == 0) {
            int row = mh * 64 + (s >> 2) * 16 + kq * 4 + (s & 3);
            merge_s[nh][row] = pk;
        }
    }
    __syncthreads();

    // ---- fused epilogue: ids, quantized, loss (2 threads per token) ----
    float l = 0.f;
    {
        int tl = tid >> 1, qv = tid & 1;
        int p  = tile * TOKS_ + tl;
        if (p < nact) {
            int tok = list[p];
            u64 qa = merge_s[0][tl], qb = merge_s[1][tl];
            u64 qm = (qb < qa) ? qb : qa;
            int id  = (int)(qm & 0xFFFFFFFFull);
            const float4* cr = (const float4*)(cb + ((size_t)id * G_ + g) * D_) + qv * 8;
            const float4* xr = (const float4*)(inp + (size_t)tok * (G_ * D_) + g * D_) + qv * 8;
            float4* qo = (float4*)(out_q + (size_t)tok * (G_ * D_) + g * D_) + qv * 8;
#pragma unroll
            for (int k = 0; k < 8; ++k) {
                float4 cc = cr[k], xx = xr[k];
                float dx = cc.x - xx.x, dy = cc.y - xx.y;
                float dz = cc.z - xx.z, dw = cc.w - xx.w;
                l += dx * dx + dy * dy + dz * dz + dw * dw;
                qo[k] = cc;
            }
            if (qv == 0) out_ids[(size_t)tok * G_ + g] = (float)id;
        }
    }
#pragma unroll
    for (int off = 32; off > 0; off >>= 1) l += __shfl_down(l, off, 64);
    if (lane == 0) {
        int slot = ((blockIdx.y * gridDim.x + blockIdx.x) * 4 + w) & (NSLOT_ - 1);
        atomicAdd(&part[slot], l);
    }
}

__global__ void finalize_kernel(const float* __restrict__ part,
                                const int* __restrict__ cnt,
                                float* __restrict__ out_losses) {
    int lane = threadIdx.x;                    // one wave of 64
    float l = part[lane] + part[lane + 64];
#pragma unroll
    for (int off = 32; off > 0; off >>= 1) l += __shfl_down(l, off, 64);
    if (lane == 0) {
        float k = l / (float)cnt[0];
        out_losses[0] = k;        // kmeans_loss
        out_losses[1] = k;        // commitment_loss (numerically identical)
        out_losses[2] = 2.f * k;  // total (BETA=1)
    }
}

extern "C" void kernel_launch(void* const* d_in, const int* in_sizes, int n_in,
                              void* d_out, int out_size, void* d_ws, size_t ws_size,
                              hipStream_t stream) {
    const float* inp = (const float*)d_in[0];   // (8,2048,512) f32
    const int*   pad = (const int*)d_in[1];     // (8,2048) i32
    const float* cb  = (const float*)d_in[2];   // (1024,8,64) f32

    float* out   = (float*)d_out;
    float* o_ids = out;                              // B*T*G
    float* o_q   = out + (size_t)BT_ * G_;           // B*T*G*D
    float* o_ls  = o_q + (size_t)BT_ * G_ * D_;      // 3 scalars

    float*     part = (float*)d_ws;
    int*       cnt  = (int*)((char*)d_ws + 512);
    float*     csqT = (float*)((char*)d_ws + 1024);
    int*       list = (int*)((char*)d_ws + 33792);
    _Float16*  cbH  = (_Float16*)((char*)d_ws + 131072);
    _Float16*  cbL  = (_Float16*)((char*)d_ws + 131072 + 1048576);

    hipMemsetAsync(d_ws, 0, 1024, stream);

    prep_csq<<<dim3(256), dim3(256), 0, stream>>>(
        cb, pad, csqT, cnt, list, o_ids, o_q, cbH, cbL);

    dim3 grid(BT_ / TOKS_, G_);                // worst-case 128-token tiles x g
    vq_scan<<<grid, dim3(TPB_), 0, stream>>>(
        inp, cb, csqT, cnt, list, cbH, cbL, o_ids, o_q, part);

    finalize_kernel<<<1, dim3(64), 0, stream>>>(part, cnt, o_ls);
}

// Round 12
// 130.902 us; speedup vs baseline: 1.0023x; 1.0023x over previous
//
#include <hip/hip_runtime.h>
#include <cfloat>
#include <stdint.h>

// KmeansVectorQuantizer: B=8, T=2048, G=8, D=64, V=1024
// Outputs (flat f32): ids[B*T*G], quantized_st[B*T*G*D], kmeans, commit, total
#define G_ 8
#define D_ 64
#define V_ 1024
#define BT_ 16384
#define TPB_ 256              // vq_scan: 4 waves
#define NSLOT_ 128            // spread loss-accumulator slots
#define TOKS_ 128             // tokens per scan block
#define NC_ 64                // codewords per chunk
#define NB_ 4                 // LDS chunk buffers (3-deep prefetch)
#define NCHUNK_ (V_ / NC_)    // 16 chunks
#define NTG_ 64               // tile-groups (grid.x): exactly 2 blocks/CU

typedef unsigned long long u64;
typedef uint32_t u32;
typedef _Float16 h8 __attribute__((ext_vector_type(8)));
typedef float f32x4 __attribute__((ext_vector_type(4)));

typedef __attribute__((address_space(3))) uint32_t lds_u32;
typedef __attribute__((address_space(1))) uint32_t glb_u32;

// global->LDS DMA, 16B per lane; LDS dest = wave-uniform base + lane*16
#define GL2LDS(gsrc, ldst) \
    __builtin_amdgcn_global_load_lds((glb_u32*)(gsrc), (lds_u32*)(ldst), 16, 0, 0)

// ws layout (bytes):
//   [0..511]     float part[128]        loss partial slots (memset 0)
//   [512..515]   int   cnt_active       (memset 0)
//   [1024)       float csqT[G_*V_]      32 KB  (transposed [g][v])
//   [33792)      int   list[BT_]        64 KB
//   [131072)     f16   cbH[G_*V_*64]    1 MB   codebook hi, GROUP-MAJOR [g][v][d]
//   [1179648)    f16   cbL[G_*V_*64]    1 MB   codebook lo*2^12, [g][v][d]

// Full-device prep (R8/R9): 256 blocks x 256 thr.
__global__ __launch_bounds__(256) void prep_csq(
        const float* __restrict__ cb, const int* __restrict__ pad,
        float* __restrict__ csqT,
        int* __restrict__ cnt, int* __restrict__ list,
        float* __restrict__ out_ids, float* __restrict__ out_q,
        _Float16* __restrict__ cbH, _Float16* __restrict__ cbL) {
    const int tid = threadIdx.x;
    const int bx  = blockIdx.x;              // 0..255
    const int lane = tid & 63, w = tid >> 6;

    // ---- Phase A: codebook convert + csq (group-major store) ----
    {
        const int gid = bx * 256 + tid;      // 0..65535
        const int row = gid >> 3;            // (v,g) row, 0..8191  (= v*8+g)
        const int seg = gid & 7;             // 8-elem segment within row
        const int v   = row >> 3, gg = row & 7;
        const float4* r = (const float4*)(cb + (size_t)row * 64 + seg * 8);
        float4 c0 = r[0], c1 = r[1];
        float xs[8] = {c0.x, c0.y, c0.z, c0.w, c1.x, c1.y, c1.z, c1.w};
        h8 hv, lv;
        float s = 0.f;
#pragma unroll
        for (int e = 0; e < 8; ++e) {
            s += xs[e] * xs[e];
            _Float16 hh = (_Float16)xs[e];
            hv[e] = hh;
            lv[e] = (_Float16)((xs[e] - (float)hh) * 4096.f);
        }
        const size_t dst = ((size_t)gg * V_ + v) * 64 + seg * 8;
        *(h8*)(cbH + dst) = hv;
        *(h8*)(cbL + dst) = lv;
        s += __shfl_xor(s, 1, 64);           // row's 8 lanes are consecutive
        s += __shfl_xor(s, 2, 64);
        s += __shfl_xor(s, 4, 64);
        if (seg == 0) csqT[gg * V_ + v] = s;
    }

    // ---- Phase B: compaction of this block's 64 tokens (wave 0) ----
    __shared__ int s_plist[64];
    __shared__ int s_npl;
    if (w == 0) {
        int tok = bx * 64 + lane;
        bool active = (pad[tok] == 0);
        u64 bal = __ballot(active);
        int na  = __popcll(bal);
        int base = 0;
        if (lane == 0) base = atomicAdd(cnt, na);
        base = __shfl(base, 0, 64);
        const u64 mb = ((u64)1 << lane) - 1;
        if (active) list[base + __popcll(bal & mb)] = tok;
        else        s_plist[__popcll(~bal & mb)] = tok;
        if (lane == 0) s_npl = 64 - na;
    }
    __syncthreads();

    // ---- Phase C: zero-fill padded tokens (2 KB per wave-iter, coalesced) --
    const int npl = s_npl;
    for (int i = w; i < npl; i += 4) {
        int tok = s_plist[i];
        float4 z = make_float4(0.f, 0.f, 0.f, 0.f);
        float4* q = (float4*)(out_q + (size_t)tok * (G_ * D_)) + lane * 2;
        q[0] = z;
        q[1] = z;
        if (lane < G_) out_ids[(size_t)tok * G_ + lane] = -1.0f;
    }
}

// MFMA scan, R12 (= R11 resubmit): EVEN-PLACEMENT grid. Exactly 512 blocks --
// grid (64, 8) -- so every CU gets 2 resident blocks in the CP's initial
// deterministic sweep and there are NO dud blocks perturbing slot refill.
// Each block grid-strides tiles (tile = bx; tile*128 < nact; tile += 64):
// 1 tile/block normally, a 2nd remainder tile on blocks (0..k, g) when
// nact > 8192. Audit notes (hang-safety): nact/tile are block-uniform ->
// uniform barriers; tile t drains vmcnt(0) at c=15, tile t+1's A-frag loads
// are auto-waited during conversion, so the chunk loop's vmcnt(8) counts
// exactly the 12 prologue DMAs (same accounting as the R9 kernel that
// passed); tile t+1's prologue writes BH[0..2] whose last readers (chunks
// 12-14) are behind tile t's c=15 barrier + merge __syncthreads().
// Per-tile body is R9 verbatim -> ids bit-exact; csq hoisted out of the loop.
__global__ __launch_bounds__(TPB_, 2) void vq_scan(
    const float* __restrict__ inp,
    const float* __restrict__ cb,
    const float* __restrict__ csqT,
    const int* __restrict__ cnt,
    const int* __restrict__ list,
    const _Float16* __restrict__ cbH,
    const _Float16* __restrict__ cbL,
    float* __restrict__ out_ids,
    float* __restrict__ out_q,
    float* __restrict__ part) {

    __shared__ __align__(16) unsigned char BH[NB_][NC_ * 128]; // 32 KB f16 hi
    __shared__ __align__(16) unsigned char BL[NB_][NC_ * 128]; // 32 KB f16 lo
    __shared__ float csq_s[V_];                                //  4 KB
    __shared__ u64 merge_s[2][TOKS_];                          //  2 KB

    const int nact = cnt[0];
    const int g    = blockIdx.y;
    const int tid  = threadIdx.x;
    const int lane = tid & 63;
    const int w    = tid >> 6;          // 0..3
    const int mh   = w >> 1;            // token half  (0..1)
    const int nh   = w & 1;             // column half (0..1)
    const int r16  = lane & 15;
    const int kq   = lane >> 4;

    // per-lane DMA source (group-major): chunk c of group g = 64 consecutive
    // 128B rows at cbH + g*131072 + c*8192. LDS linear L = w*2048 + i*1024 +
    // lane*16 -> row r = w*16 + i*8 + (lane>>3), blk = lane&7; inverse-swizzle
    // the source 16B block so LDS[r][blk] = logical[r][blk ^ (r&7)]
    // (r&7 == lane>>3 here). Lanes 0..7 span one 128B line -> coalesced.
    const size_t soff = (size_t)(w * 16 + (lane >> 3)) * 128
                      + (size_t)(((lane & 7) ^ (lane >> 3)) * 16);
    const unsigned char* sH = (const unsigned char*)cbH + (size_t)g * 131072 + soff;
    const unsigned char* sL = (const unsigned char*)cbL + (size_t)g * 131072 + soff;
    const int ldsb = w * 2048;

    // csq staged ONCE per block (amortized over this block's tiles)
    csq_s[tid]       = csqT[g * V_ + tid];
    csq_s[tid + 256] = csqT[g * V_ + tid + 256];
    csq_s[tid + 512] = csqT[g * V_ + tid + 512];
    csq_s[tid + 768] = csqT[g * V_ + tid + 768];
    asm volatile("s_waitcnt lgkmcnt(0)" ::: "memory");

    // b-frag logical byte = col*128 + kq*16 (col = nh*32 + cf*16 + r16),
    // swizzle ^((col&7)<<4) = ^((r16&7)<<4); kfrag flips bit 6 post-swizzle
    const u32 o0 = (u32)((((nh * 32 + r16) * 128 + kq * 16))
                         ^ ((u32)(r16 & 7) << 4));

    for (int tile = blockIdx.x; tile * TOKS_ < nact; tile += NTG_) {

        // ---- A fragments FIRST (their waits don't drain the DMA queue) ----
        h8 AH[4][2], AL[4][2];
#pragma unroll
        for (int rf = 0; rf < 4; ++rf) {
            int p = tile * TOKS_ + mh * 64 + rf * 16 + r16;
            int tok = list[p < nact ? p : 0];
            const float* xr = inp + (size_t)tok * (G_ * D_) + g * D_;
#pragma unroll
            for (int kf = 0; kf < 2; ++kf) {
                const float4* xp = (const float4*)(xr + kf * 32 + kq * 8);
                float4 a = xp[0], b = xp[1];
                float xs[8] = {a.x, a.y, a.z, a.w, b.x, b.y, b.z, b.w};
#pragma unroll
                for (int e = 0; e < 8; ++e) {
                    _Float16 hh = (_Float16)xs[e];
                    AH[rf][kf][e] = hh;
                    AL[rf][kf][e] = (_Float16)((xs[e] - (float)hh) * 4096.f);
                }
            }
        }

        // ---- prologue: issue chunks 0,1,2 (12 loads/wave in flight) ----
#pragma unroll
        for (int c0 = 0; c0 < 3; ++c0) {
            const size_t adv = (size_t)c0 * 8192;    // 64 rows * 128 B
            GL2LDS(sH + adv,        &BH[c0][ldsb]);
            GL2LDS(sH + adv + 1024, &BH[c0][ldsb + 1024]);
            GL2LDS(sL + adv,        &BL[c0][ldsb]);
            GL2LDS(sL + adv + 1024, &BL[c0][ldsb + 1024]);
        }

        float beste[16];
        int   bestid[16];
#pragma unroll
        for (int s = 0; s < 16; ++s) { beste[s] = -FLT_MAX / 2; bestid[s] = 0; }

#pragma unroll 1
        for (int c = 0; c < NCHUNK_; ++c) {
            // fused counted-wait + barrier (single asm: nothing slips between)
            // vmcnt(8): 2 newest chunks stay in flight; chunk c is landed.
            if (c < NCHUNK_ - 2)
                asm volatile("s_waitcnt vmcnt(8)\n\ts_barrier" ::: "memory");
            else if (c == NCHUNK_ - 2)
                asm volatile("s_waitcnt vmcnt(4)\n\ts_barrier" ::: "memory");
            else
                asm volatile("s_waitcnt vmcnt(0)\n\ts_barrier" ::: "memory");
            __builtin_amdgcn_sched_barrier(0);

            if (c + 3 < NCHUNK_) {           // prefetch 3 ahead (post-barrier)
                const int b = (c + 3) & (NB_ - 1);
                const size_t adv = (size_t)(c + 3) * 8192;
                GL2LDS(sH + adv,        &BH[b][ldsb]);
                GL2LDS(sH + adv + 1024, &BH[b][ldsb + 1024]);
                GL2LDS(sL + adv,        &BL[b][ldsb]);
                GL2LDS(sL + adv + 1024, &BL[b][ldsb + 1024]);
            }

            const unsigned char* BHc = &BH[c & (NB_ - 1)][0];
            const unsigned char* BLc = &BL[c & (NB_ - 1)][0];
#pragma unroll
            for (int cf = 0; cf < 2; ++cf) {
                const u32 ob = o0 + (u32)(cf * 2048);
                const h8 bh0 = *(const h8*)(BHc + ob);
                const h8 bh1 = *(const h8*)(BHc + (ob ^ 64));
                const h8 bl0 = *(const h8*)(BLc + ob);
                const h8 bl1 = *(const h8*)(BLc + (ob ^ 64));
                const int vcol = c * NC_ + nh * 32 + cf * 16 + r16;
                const float ai = -0.5f * csq_s[vcol];
#pragma unroll
                for (int rf = 0; rf < 4; ++rf) {
                    f32x4 a  = {ai, ai, ai, ai};
                    f32x4 ac = {0.f, 0.f, 0.f, 0.f};
                    a  = __builtin_amdgcn_mfma_f32_16x16x32_f16(AH[rf][0], bh0, a,  0, 0, 0);
                    a  = __builtin_amdgcn_mfma_f32_16x16x32_f16(AH[rf][1], bh1, a,  0, 0, 0);
                    ac = __builtin_amdgcn_mfma_f32_16x16x32_f16(AH[rf][0], bl0, ac, 0, 0, 0);
                    ac = __builtin_amdgcn_mfma_f32_16x16x32_f16(AH[rf][1], bl1, ac, 0, 0, 0);
                    ac = __builtin_amdgcn_mfma_f32_16x16x32_f16(AL[rf][0], bh0, ac, 0, 0, 0);
                    ac = __builtin_amdgcn_mfma_f32_16x16x32_f16(AL[rf][1], bh1, ac, 0, 0, 0);
#pragma unroll
                    for (int q = 0; q < 4; ++q) {
                        // e = -d/2 exactly; argmax e == argmin d, ties -> first
                        float e = fmaf(0x1.0p-12f, ac[q], a[q]);
                        int s = rf * 4 + q;
                        if (e > beste[s]) { beste[s] = e; bestid[s] = vcol; }
                    }
                }
            }
        }

        // ---- cross-lane argmin (16-lane butterfly) + cross-nh merge ----
#pragma unroll
        for (int s = 0; s < 16; ++s) {
            float d = -2.f * beste[s];
            u32 u = __float_as_uint(d);
            u = u ^ ((u >> 31) ? 0xFFFFFFFFu : 0x80000000u);   // sortable float
            u64 pk = ((u64)u << 32) | (u32)bestid[s];
#pragma unroll
            for (int off = 1; off <= 8; off <<= 1) {
                u64 o = __shfl_xor(pk, off, 64);
                pk = (o < pk) ? o : pk;
            }
            if (r16 == 0) {
                int row = mh * 64 + (s >> 2) * 16 + kq * 4 + (s & 3);
                merge_s[nh][row] = pk;
            }
        }
        __syncthreads();

        // ---- fused epilogue: ids, quantized, loss (2 threads per token) ----
        float l = 0.f;
        {
            int tl = tid >> 1, qv = tid & 1;
            int p  = tile * TOKS_ + tl;
            if (p < nact) {
                int tok = list[p];
                u64 qa = merge_s[0][tl], qb = merge_s[1][tl];
                u64 qm = (qb < qa) ? qb : qa;
                int id  = (int)(qm & 0xFFFFFFFFull);
                const float4* cr = (const float4*)(cb + ((size_t)id * G_ + g) * D_) + qv * 8;
                const float4* xr = (const float4*)(inp + (size_t)tok * (G_ * D_) + g * D_) + qv * 8;
                float4* qo = (float4*)(out_q + (size_t)tok * (G_ * D_) + g * D_) + qv * 8;
#pragma unroll
                for (int k = 0; k < 8; ++k) {
                    float4 cc = cr[k], xx = xr[k];
                    float dx = cc.x - xx.x, dy = cc.y - xx.y;
                    float dz = cc.z - xx.z, dw = cc.w - xx.w;
                    l += dx * dx + dy * dy + dz * dz + dw * dw;
                    qo[k] = cc;
                }
                if (qv == 0) out_ids[(size_t)tok * G_ + g] = (float)id;
            }
        }
#pragma unroll
        for (int off = 32; off > 0; off >>= 1) l += __shfl_down(l, off, 64);
        if (lane == 0) {
            int slot = ((blockIdx.y * NTG_ + blockIdx.x) * 4 + w) & (NSLOT_ - 1);
            atomicAdd(&part[slot], l);
        }
        // next tile's merge_s writes are ordered behind 16 chunk barriers ->
        // no wave can overwrite merge_s while another still reads it.
    }
}

__global__ void finalize_kernel(const float* __restrict__ part,
                                const int* __restrict__ cnt,
                                float* __restrict__ out_losses) {
    int lane = threadIdx.x;                    // one wave of 64
    float l = part[lane] + part[lane + 64];
#pragma unroll
    for (int off = 32; off > 0; off >>= 1) l += __shfl_down(l, off, 64);
    if (lane == 0) {
        float k = l / (float)cnt[0];
        out_losses[0] = k;        // kmeans_loss
        out_losses[1] = k;        // commitment_loss (numerically identical)
        out_losses[2] = 2.f * k;  // total (BETA=1)
    }
}

extern "C" void kernel_launch(void* const* d_in, const int* in_sizes, int n_in,
                              void* d_out, int out_size, void* d_ws, size_t ws_size,
                              hipStream_t stream) {
    const float* inp = (const float*)d_in[0];   // (8,2048,512) f32
    const int*   pad = (const int*)d_in[1];     // (8,2048) i32
    const float* cb  = (const float*)d_in[2];   // (1024,8,64) f32

    float* out   = (float*)d_out;
    float* o_ids = out;                              // B*T*G
    float* o_q   = out + (size_t)BT_ * G_;           // B*T*G*D
    float* o_ls  = o_q + (size_t)BT_ * G_ * D_;      // 3 scalars

    float*     part = (float*)d_ws;
    int*       cnt  = (int*)((char*)d_ws + 512);
    float*     csqT = (float*)((char*)d_ws + 1024);
    int*       list = (int*)((char*)d_ws + 33792);
    _Float16*  cbH  = (_Float16*)((char*)d_ws + 131072);
    _Float16*  cbL  = (_Float16*)((char*)d_ws + 131072 + 1048576);

    hipMemsetAsync(d_ws, 0, 1024, stream);

    prep_csq<<<dim3(256), dim3(256), 0, stream>>>(
        cb, pad, csqT, cnt, list, o_ids, o_q, cbH, cbL);

    // exactly 2 blocks/CU, no dud blocks; tiles grid-strided inside
    vq_scan<<<dim3(NTG_, G_), dim3(TPB_), 0, stream>>>(
        inp, cb, csqT, cnt, list, cbH, cbL, o_ids, o_q, part);

    finalize_kernel<<<1, dim3(64), 0, stream>>>(part, cnt, o_ls);
}

// Round 14
// 127.536 us; speedup vs baseline: 1.0288x; 1.0264x over previous
//
#include <hip/hip_runtime.h>
#include <cfloat>
#include <stdint.h>

// KmeansVectorQuantizer: B=8, T=2048, G=8, D=64, V=1024
// Outputs (flat f32): ids[B*T*G], quantized_st[B*T*G*D], kmeans, commit, total
//
// FINAL (R14 = R9 restore, best measured: 128.25 us total, scan 44-45 us).
// Session ledger: MFMA f16 hi/lo emulation of the fp32 distance scan (exact
// argmin preserved; lo pre-scaled 2^12, cq folded into accumulator seed),
// zero-spill register budget, full-device prep (65k threads), group-major
// pre-split codebook for coalesced global_load_lds staging, counted-vmcnt
// 3-deep chunk pipeline. Falsified scan levers (time invariant 43-49 us):
// occupancy 2->4 blk/CU, pipeline depth 1->3, DMA gather pattern, in-loop
// barriers, placement/grid shape. Dispatch fusion blocked by harness graph
// capture (R13: cooperative launch never executes; R3: done-counter crashed).
#define G_ 8
#define D_ 64
#define V_ 1024
#define BT_ 16384
#define TPB_ 256              // vq_scan: 4 waves
#define NSLOT_ 128            // spread loss-accumulator slots
#define TOKS_ 128             // tokens per scan block
#define NC_ 64                // codewords per chunk
#define NB_ 4                 // LDS chunk buffers (3-deep prefetch)
#define NCHUNK_ (V_ / NC_)    // 16 chunks

typedef unsigned long long u64;
typedef uint32_t u32;
typedef _Float16 h8 __attribute__((ext_vector_type(8)));
typedef float f32x4 __attribute__((ext_vector_type(4)));

typedef __attribute__((address_space(3))) uint32_t lds_u32;
typedef __attribute__((address_space(1))) uint32_t glb_u32;

// global->LDS DMA, 16B per lane; LDS dest = wave-uniform base + lane*16
#define GL2LDS(gsrc, ldst) \
    __builtin_amdgcn_global_load_lds((glb_u32*)(gsrc), (lds_u32*)(ldst), 16, 0, 0)

// ws layout (bytes):
//   [0..511]     float part[128]        loss partial slots (memset 0)
//   [512..515]   int   cnt_active       (memset 0)
//   [1024)       float csqT[G_*V_]      32 KB  (transposed [g][v])
//   [33792)      int   list[BT_]        64 KB
//   [131072)     f16   cbH[G_*V_*64]    1 MB   codebook hi, GROUP-MAJOR [g][v][d]
//   [1179648)    f16   cbL[G_*V_*64]    1 MB   codebook lo*2^12, [g][v][d]

// Full-device prep: 256 blocks x 256 thr.
// Phase A: one thread per 8 codebook elems -- coalesced f32x8 load, f16 hi/lo
//          convert (stored group-major), csq row-sum via 3-step shfl_xor.
// Phase B: each block compacts its 64 tokens (wave 0: ballot + 1 atomicAdd;
//          list order is irrelevant -- outputs are indexed by token).
// Phase C: coalesced zero-fill of padded tokens.
__global__ __launch_bounds__(256) void prep_csq(
        const float* __restrict__ cb, const int* __restrict__ pad,
        float* __restrict__ csqT,
        int* __restrict__ cnt, int* __restrict__ list,
        float* __restrict__ out_ids, float* __restrict__ out_q,
        _Float16* __restrict__ cbH, _Float16* __restrict__ cbL) {
    const int tid = threadIdx.x;
    const int bx  = blockIdx.x;              // 0..255
    const int lane = tid & 63, w = tid >> 6;

    // ---- Phase A: codebook convert + csq (group-major store) ----
    {
        const int gid = bx * 256 + tid;      // 0..65535
        const int row = gid >> 3;            // (v,g) row, 0..8191  (= v*8+g)
        const int seg = gid & 7;             // 8-elem segment within row
        const int v   = row >> 3, gg = row & 7;
        const float4* r = (const float4*)(cb + (size_t)row * 64 + seg * 8);
        float4 c0 = r[0], c1 = r[1];
        float xs[8] = {c0.x, c0.y, c0.z, c0.w, c1.x, c1.y, c1.z, c1.w};
        h8 hv, lv;
        float s = 0.f;
#pragma unroll
        for (int e = 0; e < 8; ++e) {
            s += xs[e] * xs[e];
            _Float16 hh = (_Float16)xs[e];
            hv[e] = hh;
            lv[e] = (_Float16)((xs[e] - (float)hh) * 4096.f);
        }
        const size_t dst = ((size_t)gg * V_ + v) * 64 + seg * 8;
        *(h8*)(cbH + dst) = hv;
        *(h8*)(cbL + dst) = lv;
        s += __shfl_xor(s, 1, 64);           // row's 8 lanes are consecutive
        s += __shfl_xor(s, 2, 64);
        s += __shfl_xor(s, 4, 64);
        if (seg == 0) csqT[gg * V_ + v] = s;
    }

    // ---- Phase B: compaction of this block's 64 tokens (wave 0) ----
    __shared__ int s_plist[64];
    __shared__ int s_npl;
    if (w == 0) {
        int tok = bx * 64 + lane;
        bool active = (pad[tok] == 0);
        u64 bal = __ballot(active);
        int na  = __popcll(bal);
        int base = 0;
        if (lane == 0) base = atomicAdd(cnt, na);
        base = __shfl(base, 0, 64);
        const u64 mb = ((u64)1 << lane) - 1;
        if (active) list[base + __popcll(bal & mb)] = tok;
        else        s_plist[__popcll(~bal & mb)] = tok;
        if (lane == 0) s_npl = 64 - na;
    }
    __syncthreads();

    // ---- Phase C: zero-fill padded tokens (2 KB per wave-iter, coalesced) --
    const int npl = s_npl;
    for (int i = w; i < npl; i += 4) {
        int tok = s_plist[i];
        float4 z = make_float4(0.f, 0.f, 0.f, 0.f);
        float4* q = (float4*)(out_q + (size_t)tok * (G_ * D_)) + lane * 2;
        q[0] = z;
        q[1] = z;
        if (lane < G_) out_ids[(size_t)tok * G_ + lane] = -1.0f;
    }
}

// MFMA scan: block = 128 tok x 1024 cw (one g), 4 waves (mh x nh); chunks of
// 64 cw in 4 LDS buffers, DMA'd 3 ahead via global_load_lds from the group-
// major pre-split codebook (fully coalesced 1KB per instruction). Per chunk
// iteration: fused {s_waitcnt vmcnt(8); s_barrier} single asm (oldest chunk
// landed; 2 newer stay in flight -- never drain to 0 in-loop), then issue
// chunk c+3, then compute. fp32 emulated as f16 hi/lo (lo pre-scaled 2^12;
// separate cross accumulator); cq folded into the hh accumulator seed
// (-cq/2); fold = argmax of e = a + 2^-12*ac (exact -d/2). XOR-swizzled LDS
// via inverse-swizzled global source (read-side ^((row&7)<<4); 0 conflicts).
__global__ __launch_bounds__(TPB_, 2) void vq_scan(
    const float* __restrict__ inp,
    const float* __restrict__ cb,
    const float* __restrict__ csqT,
    const int* __restrict__ cnt,
    const int* __restrict__ list,
    const _Float16* __restrict__ cbH,
    const _Float16* __restrict__ cbL,
    float* __restrict__ out_ids,
    float* __restrict__ out_q,
    float* __restrict__ part) {

    __shared__ __align__(16) unsigned char BH[NB_][NC_ * 128]; // 32 KB f16 hi
    __shared__ __align__(16) unsigned char BL[NB_][NC_ * 128]; // 32 KB f16 lo
    __shared__ float csq_s[V_];                                //  4 KB
    __shared__ u64 merge_s[2][TOKS_];                          //  2 KB

    const int nact = cnt[0];
    const int tile = blockIdx.x;
    if (tile * TOKS_ >= nact) return;          // uniform early-exit (pre-barrier)
    const int g    = blockIdx.y;
    const int tid  = threadIdx.x;
    const int lane = tid & 63;
    const int w    = tid >> 6;          // 0..3
    const int mh   = w >> 1;            // token half  (0..1)
    const int nh   = w & 1;             // column half (0..1)
    const int r16  = lane & 15;
    const int kq   = lane >> 4;

    // ---- A fragments FIRST (their waitcnts then don't drain the DMA queue) --
    h8 AH[4][2], AL[4][2];
#pragma unroll
    for (int rf = 0; rf < 4; ++rf) {
        int p = tile * TOKS_ + mh * 64 + rf * 16 + r16;
        int tok = list[p < nact ? p : 0];
        const float* xr = inp + (size_t)tok * (G_ * D_) + g * D_;
#pragma unroll
        for (int kf = 0; kf < 2; ++kf) {
            const float4* xp = (const float4*)(xr + kf * 32 + kq * 8);
            float4 a = xp[0], b = xp[1];
            float xs[8] = {a.x, a.y, a.z, a.w, b.x, b.y, b.z, b.w};
#pragma unroll
            for (int e = 0; e < 8; ++e) {
                _Float16 hh = (_Float16)xs[e];
                AH[rf][kf][e] = hh;
                AL[rf][kf][e] = (_Float16)((xs[e] - (float)hh) * 4096.f);
            }
        }
    }

    // per-lane DMA source (group-major): chunk c of group g = 64 consecutive
    // 128B rows at cbH + g*131072 + c*8192. LDS linear L = w*2048 + i*1024 +
    // lane*16 -> row r = w*16 + i*8 + (lane>>3), blk = lane&7; inverse-swizzle
    // the source 16B block so LDS[r][blk] = logical[r][blk ^ (r&7)]
    // (r&7 == lane>>3 here). Lanes 0..7 span one 128B line -> coalesced.
    const size_t soff = (size_t)(w * 16 + (lane >> 3)) * 128
                      + (size_t)(((lane & 7) ^ (lane >> 3)) * 16);
    const unsigned char* sH = (const unsigned char*)cbH + (size_t)g * 131072 + soff;
    const unsigned char* sL = (const unsigned char*)cbL + (size_t)g * 131072 + soff;
    const int ldsb = w * 2048;

    // ---- prologue: issue chunks 0,1,2 (12 loads/wave in flight) ----
#pragma unroll
    for (int c0 = 0; c0 < 3; ++c0) {
        const size_t adv = (size_t)c0 * 8192;    // 64 rows * 128 B
        GL2LDS(sH + adv,        &BH[c0][ldsb]);
        GL2LDS(sH + adv + 1024, &BH[c0][ldsb + 1024]);
        GL2LDS(sL + adv,        &BL[c0][ldsb]);
        GL2LDS(sL + adv + 1024, &BL[c0][ldsb + 1024]);
    }

    csq_s[tid]       = csqT[g * V_ + tid];
    csq_s[tid + 256] = csqT[g * V_ + tid + 256];
    csq_s[tid + 512] = csqT[g * V_ + tid + 512];
    csq_s[tid + 768] = csqT[g * V_ + tid + 768];

    float beste[16];
    int   bestid[16];
#pragma unroll
    for (int s = 0; s < 16; ++s) { beste[s] = -FLT_MAX / 2; bestid[s] = 0; }

    // csq_s ds_writes must be complete before the first barrier
    asm volatile("s_waitcnt lgkmcnt(0)" ::: "memory");

    // b-frag logical byte = col*128 + kq*16 (col = nh*32 + cf*16 + r16),
    // swizzle ^((col&7)<<4) = ^((r16&7)<<4); kfrag flips bit 6 post-swizzle
    const u32 o0 = (u32)((((nh * 32 + r16) * 128 + kq * 16))
                         ^ ((u32)(r16 & 7) << 4));

#pragma unroll 1
    for (int c = 0; c < NCHUNK_; ++c) {
        // fused counted-wait + barrier: no memory op may cross (single asm).
        // vmcnt(8): 2 newest chunks may stay in flight; chunk c is landed.
        if (c < NCHUNK_ - 2)
            asm volatile("s_waitcnt vmcnt(8)\n\ts_barrier" ::: "memory");
        else if (c == NCHUNK_ - 2)
            asm volatile("s_waitcnt vmcnt(4)\n\ts_barrier" ::: "memory");
        else
            asm volatile("s_waitcnt vmcnt(0)\n\ts_barrier" ::: "memory");
        __builtin_amdgcn_sched_barrier(0);

        if (c + 3 < NCHUNK_) {             // prefetch 3 ahead (post-barrier:
            const int b = (c + 3) & (NB_ - 1);   // target buffer's readers done)
            const size_t adv = (size_t)(c + 3) * 8192;
            GL2LDS(sH + adv,        &BH[b][ldsb]);
            GL2LDS(sH + adv + 1024, &BH[b][ldsb + 1024]);
            GL2LDS(sL + adv,        &BL[b][ldsb]);
            GL2LDS(sL + adv + 1024, &BL[b][ldsb + 1024]);
        }

        const unsigned char* BHc = &BH[c & (NB_ - 1)][0];
        const unsigned char* BLc = &BL[c & (NB_ - 1)][0];
#pragma unroll
        for (int cf = 0; cf < 2; ++cf) {
            const u32 ob = o0 + (u32)(cf * 2048);
            const h8 bh0 = *(const h8*)(BHc + ob);
            const h8 bh1 = *(const h8*)(BHc + (ob ^ 64));
            const h8 bl0 = *(const h8*)(BLc + ob);
            const h8 bl1 = *(const h8*)(BLc + (ob ^ 64));
            const int vcol = c * NC_ + nh * 32 + cf * 16 + r16;
            const float ai = -0.5f * csq_s[vcol];
#pragma unroll
            for (int rf = 0; rf < 4; ++rf) {
                f32x4 a  = {ai, ai, ai, ai};
                f32x4 ac = {0.f, 0.f, 0.f, 0.f};
                a  = __builtin_amdgcn_mfma_f32_16x16x32_f16(AH[rf][0], bh0, a,  0, 0, 0);
                a  = __builtin_amdgcn_mfma_f32_16x16x32_f16(AH[rf][1], bh1, a,  0, 0, 0);
                ac = __builtin_amdgcn_mfma_f32_16x16x32_f16(AH[rf][0], bl0, ac, 0, 0, 0);
                ac = __builtin_amdgcn_mfma_f32_16x16x32_f16(AH[rf][1], bl1, ac, 0, 0, 0);
                ac = __builtin_amdgcn_mfma_f32_16x16x32_f16(AL[rf][0], bh0, ac, 0, 0, 0);
                ac = __builtin_amdgcn_mfma_f32_16x16x32_f16(AL[rf][1], bh1, ac, 0, 0, 0);
#pragma unroll
                for (int q = 0; q < 4; ++q) {
                    // e = -d/2 exactly; argmax e == argmin d, ties -> first
                    float e = fmaf(0x1.0p-12f, ac[q], a[q]);
                    int s = rf * 4 + q;
                    if (e > beste[s]) { beste[s] = e; bestid[s] = vcol; }
                }
            }
        }
    }

    // ---- cross-lane argmin (16-lane butterfly) + cross-nh merge ----
#pragma unroll
    for (int s = 0; s < 16; ++s) {
        float d = -2.f * beste[s];
        u32 u = __float_as_uint(d);
        u = u ^ ((u >> 31) ? 0xFFFFFFFFu : 0x80000000u);   // sortable float
        u64 pk = ((u64)u << 32) | (u32)bestid[s];
#pragma unroll
        for (int off = 1; off <= 8; off <<= 1) {
            u64 o = __shfl_xor(pk, off, 64);
            pk = (o < pk) ? o : pk;
        }
        if (r16 == 0) {
            int row = mh * 64 + (s >> 2) * 16 + kq * 4 + (s & 3);
            merge_s[nh][row] = pk;
        }
    }
    __syncthreads();

    // ---- fused epilogue: ids, quantized, loss (2 threads per token) ----
    float l = 0.f;
    {
        int tl = tid >> 1, qv = tid & 1;
        int p  = tile * TOKS_ + tl;
        if (p < nact) {
            int tok = list[p];
            u64 qa = merge_s[0][tl], qb = merge_s[1][tl];
            u64 qm = (qb < qa) ? qb : qa;
            int id  = (int)(qm & 0xFFFFFFFFull);
            const float4* cr = (const float4*)(cb + ((size_t)id * G_ + g) * D_) + qv * 8;
            const float4* xr = (const float4*)(inp + (size_t)tok * (G_ * D_) + g * D_) + qv * 8;
            float4* qo = (float4*)(out_q + (size_t)tok * (G_ * D_) + g * D_) + qv * 8;
#pragma unroll
            for (int k = 0; k < 8; ++k) {
                float4 cc = cr[k], xx = xr[k];
                float dx = cc.x - xx.x, dy = cc.y - xx.y;
                float dz = cc.z - xx.z, dw = cc.w - xx.w;
                l += dx * dx + dy * dy + dz * dz + dw * dw;
                qo[k] = cc;
            }
            if (qv == 0) out_ids[(size_t)tok * G_ + g] = (float)id;
        }
    }
#pragma unroll
    for (int off = 32; off > 0; off >>= 1) l += __shfl_down(l, off, 64);
    if (lane == 0) {
        int slot = ((blockIdx.y * gridDim.x + blockIdx.x) * 4 + w) & (NSLOT_ - 1);
        atomicAdd(&part[slot], l);
    }
}

__global__ void finalize_kernel(const float* __restrict__ part,
                                const int* __restrict__ cnt,
                                float* __restrict__ out_losses) {
    int lane = threadIdx.x;                    // one wave of 64
    float l = part[lane] + part[lane + 64];
#pragma unroll
    for (int off = 32; off > 0; off >>= 1) l += __shfl_down(l, off, 64);
    if (lane == 0) {
        float k = l / (float)cnt[0];
        out_losses[0] = k;        // kmeans_loss
        out_losses[1] = k;        // commitment_loss (numerically identical)
        out_losses[2] = 2.f * k;  // total (BETA=1)
    }
}

extern "C" void kernel_launch(void* const* d_in, const int* in_sizes, int n_in,
                              void* d_out, int out_size, void* d_ws, size_t ws_size,
                              hipStream_t stream) {
    const float* inp = (const float*)d_in[0];   // (8,2048,512) f32
    const int*   pad = (const int*)d_in[1];     // (8,2048) i32
    const float* cb  = (const float*)d_in[2];   // (1024,8,64) f32

    float* out   = (float*)d_out;
    float* o_ids = out;                              // B*T*G
    float* o_q   = out + (size_t)BT_ * G_;           // B*T*G*D
    float* o_ls  = o_q + (size_t)BT_ * G_ * D_;      // 3 scalars

    float*     part = (float*)d_ws;
    int*       cnt  = (int*)((char*)d_ws + 512);
    float*     csqT = (float*)((char*)d_ws + 1024);
    int*       list = (int*)((char*)d_ws + 33792);
    _Float16*  cbH  = (_Float16*)((char*)d_ws + 131072);
    _Float16*  cbL  = (_Float16*)((char*)d_ws + 131072 + 1048576);

    hipMemsetAsync(d_ws, 0, 1024, stream);

    prep_csq<<<dim3(256), dim3(256), 0, stream>>>(
        cb, pad, csqT, cnt, list, o_ids, o_q, cbH, cbL);

    dim3 grid(BT_ / TOKS_, G_);                // worst-case 128-token tiles x g
    vq_scan<<<grid, dim3(TPB_), 0, stream>>>(
        inp, cb, csqT, cnt, list, cbH, cbL, o_ids, o_q, part);

    finalize_kernel<<<1, dim3(64), 0, stream>>>(part, cnt, o_ls);
}